// Round 5
// baseline (137.418 us; speedup 1.0000x reference)
//
#include <hip/hip_runtime.h>
#include <hip/hip_bf16.h>

#define NPOS 80
#define VOCABSZ 256
#define HID 128
#define ROWS 16
#define NT 256
#define MPAD 81      // msg row pitch (ints): conflict-free row reads
#define HPAD 136     // h row pitch (ushorts): 272B, 16B-aligned

typedef __attribute__((ext_vector_type(8))) short bf16x8;
typedef __attribute__((ext_vector_type(4))) float f32x4;
typedef __attribute__((ext_vector_type(4))) unsigned int u32x4;

__device__ __forceinline__ float elu_f(float x) {
    return x > 0.f ? x : expm1f(x);
}

__device__ __forceinline__ unsigned short f2bf(float x) {
    __hip_bfloat16 h = __float2bfloat16(x);  // RNE
    return *reinterpret_cast<unsigned short*>(&h);
}

// ============ single fused kernel: prep + grid barrier + gather + MFMA =====
// Capacity guarantee for the manual barrier: LDS 9.5KB, launch_bounds(256,8)
// -> 8 blocks/CU -> 2048 co-resident blocks >= grid (1024). Counter is
// zeroed by hipMemsetAsync before every launch (deterministic).
__global__ __launch_bounds__(NT, 8)
void topline_one(const int* __restrict__ msg,
                 const float* __restrict__ W1,
                 const float* __restrict__ b1,
                 const float* __restrict__ W2,
                 const float* __restrict__ b2,
                 float* __restrict__ out,
                 unsigned short* __restrict__ w1b,
                 unsigned short* __restrict__ w2t,
                 unsigned int* __restrict__ bar)
{
    __shared__ int msg_s[ROWS * MPAD];               // 5184 B
    __shared__ unsigned short h_s[ROWS * HPAD];      // 4352 B

    const int t = threadIdx.x;
    const int nb = gridDim.x;
    const int block_row0 = blockIdx.x * ROWS;
    const int gid = blockIdx.x * NT + t;
    const int nthr = nb * NT;

    // ---- phase A1: stage message rows (block-local) ----
    const int* mrow = msg + block_row0 * NPOS;
    #pragma unroll
    for (int i = 0; i < 5; ++i) {
        int idx = t + i * NT;                        // < 1280
        int r = idx / NPOS;
        int c = idx - r * NPOS;
        msg_s[r * MPAD + c] = mrow[idx];
    }

    // ---- phase A2: W1 fp32 -> bf16 table (grid-strided, coalesced) ----
    {
        const float4* W1v = reinterpret_cast<const float4*>(W1);
        ushort4* w1bv = reinterpret_cast<ushort4*>(w1b);
        for (int idx = gid; idx < NPOS * VOCABSZ * (HID / 4); idx += nthr) {
            float4 w = W1v[idx];
            ushort4 o;
            o.x = f2bf(w.x); o.y = f2bf(w.y); o.z = f2bf(w.z); o.w = f2bf(w.w);
            w1bv[idx] = o;
        }
    }
    // ---- phase A3: W2 transpose -> bf16 (tiny) ----
    for (int e = gid; e < HID * HID; e += nthr) {
        int k = e >> 7, n = e & 127;
        w2t[n * HID + k] = f2bf(W2[e]);              // w2t[n][k]
    }

    // ---- grid-wide arrive-and-wait barrier ----
    __syncthreads();
    if (t == 0) {
        __threadfence();                             // publish w1b/w2t
        atomicAdd(bar, 1u);
        while (__hip_atomic_load(bar, __ATOMIC_ACQUIRE, __HIP_MEMORY_SCOPE_AGENT)
               < (unsigned)nb)
            __builtin_amdgcn_s_sleep(8);
    }
    __syncthreads();

    // ---- phase B: gather, position-major sweep over bf16 table ----
    // thread (row = t>>4, lane16 = t&15) owns channels lane16*8..+7 of one row
    const int lane16 = t & 15;
    const int row    = t >> 4;
    const int mbase  = row * MPAD;
    const unsigned short* wb = w1b + lane16 * 8;     // channel offset folded in

    float acc[8];
    #pragma unroll
    for (int i = 0; i < 8; ++i) acc[i] = 0.f;

    #pragma unroll 4
    for (int p = 0; p < NPOS; ++p) {
        int c = msg_s[mbase + p];                    // broadcast across 16 lanes
        u32x4 v = *reinterpret_cast<const u32x4*>(wb + ((p * VOCABSZ + c) << 7));
        // lo bf16: shift to hi half. hi bf16: add RAW (garbage low mantissa
        // bits perturb by <2^-8 relative; validated absmax-identical in r4).
        acc[0] += __uint_as_float(v[0] << 16);
        acc[1] += __uint_as_float(v[0]);
        acc[2] += __uint_as_float(v[1] << 16);
        acc[3] += __uint_as_float(v[1]);
        acc[4] += __uint_as_float(v[2] << 16);
        acc[5] += __uint_as_float(v[2]);
        acc[6] += __uint_as_float(v[3] << 16);
        acc[7] += __uint_as_float(v[3]);
    }

    // ---- bias + elu + store h as bf16 ----
    {
        const float4 ba = reinterpret_cast<const float4*>(b1)[lane16 * 2];
        const float4 bb = reinterpret_cast<const float4*>(b1)[lane16 * 2 + 1];
        unsigned short* hp = &h_s[row * HPAD + lane16 * 8];
        hp[0] = f2bf(elu_f(acc[0] + ba.x));
        hp[1] = f2bf(elu_f(acc[1] + ba.y));
        hp[2] = f2bf(elu_f(acc[2] + ba.z));
        hp[3] = f2bf(elu_f(acc[3] + ba.w));
        hp[4] = f2bf(elu_f(acc[4] + bb.x));
        hp[5] = f2bf(elu_f(acc[5] + bb.y));
        hp[6] = f2bf(elu_f(acc[6] + bb.z));
        hp[7] = f2bf(elu_f(acc[7] + bb.w));
    }
    __syncthreads();

    // ---- MFMA: out[16,128] = elu(h @ W2 + b2); wave wv -> n-tiles 2wv,2wv+1 ----
    const int wv   = t >> 6;     // 0..3
    const int lane = t & 63;
    const int lrow = lane & 15;
    const int lhi  = lane >> 4;  // 0..3

    #pragma unroll
    for (int q = 0; q < 2; ++q) {
        int nt = wv * 2 + q;
        f32x4 c4 = {0.f, 0.f, 0.f, 0.f};
        #pragma unroll
        for (int ks = 0; ks < 4; ++ks) {
            bf16x8 a = *reinterpret_cast<const bf16x8*>(
                &h_s[lrow * HPAD + ks * 32 + lhi * 8]);
            bf16x8 bfr = *reinterpret_cast<const bf16x8*>(
                &w2t[(nt * 16 + lrow) * HID + ks * 32 + lhi * 8]);
            c4 = __builtin_amdgcn_mfma_f32_16x16x32_bf16(a, bfr, c4, 0, 0, 0);
        }
        int ncol = nt * 16 + lrow;
        float bias = b2[ncol];
        #pragma unroll
        for (int r = 0; r < 4; ++r)
            out[(block_row0 + lhi * 4 + r) * HID + ncol] = elu_f(c4[r] + bias);
    }
}

// ================= fallback (round-2 kernel, fp32 table, no ws) ===========
#define FB_ROWS 32
#define FB_NT 256

__global__ __launch_bounds__(FB_NT, 2)
void topline_fused(const int* __restrict__ msg,
                   const float* __restrict__ W1,
                   const float* __restrict__ b1,
                   const float* __restrict__ W2,
                   const float* __restrict__ b2,
                   float* __restrict__ out)
{
    __shared__ int msg_s[FB_ROWS * NPOS];
    __shared__ unsigned short h_s[FB_ROWS * HPAD];
    __shared__ unsigned short w2t_s[HID * HPAD];

    const int t = threadIdx.x;
    const int block_row0 = blockIdx.x * FB_ROWS;

    const int* mrow = msg + block_row0 * NPOS;
    #pragma unroll
    for (int i = 0; i < (FB_ROWS * NPOS) / FB_NT; ++i)
        msg_s[t + i * FB_NT] = mrow[t + i * FB_NT];

    const float4* W2v = reinterpret_cast<const float4*>(W2);
    #pragma unroll
    for (int i = 0; i < (HID * HID / 4) / FB_NT; ++i) {
        int i4 = t + i * FB_NT;
        int k  = i4 >> 5;
        int n0 = (i4 & 31) * 4;
        float4 w = W2v[i4];
        w2t_s[(n0 + 0) * HPAD + k] = f2bf(w.x);
        w2t_s[(n0 + 1) * HPAD + k] = f2bf(w.y);
        w2t_s[(n0 + 2) * HPAD + k] = f2bf(w.z);
        w2t_s[(n0 + 3) * HPAD + k] = f2bf(w.w);
    }
    __syncthreads();

    const int lane32 = t & 31;
    const int slot   = t >> 5;
    const int row0   = slot * 4;
    const float4* W1v = reinterpret_cast<const float4*>(W1);

    f32x4 acc[4];
    #pragma unroll
    for (int r = 0; r < 4; ++r) acc[r] = (f32x4){0.f, 0.f, 0.f, 0.f};

    #pragma unroll 2
    for (int p = 0; p < NPOS; ++p) {
        #pragma unroll
        for (int r = 0; r < 4; ++r) {
            int c = msg_s[(row0 + r) * NPOS + p];
            float4 w = W1v[(p * VOCABSZ + c) * (HID / 4) + lane32];
            acc[r].x += w.x; acc[r].y += w.y; acc[r].z += w.z; acc[r].w += w.w;
        }
    }

    const float4 bv = reinterpret_cast<const float4*>(b1)[lane32];
    #pragma unroll
    for (int r = 0; r < 4; ++r) {
        unsigned short* hp = &h_s[(row0 + r) * HPAD + lane32 * 4];
        hp[0] = f2bf(elu_f(acc[r].x + bv.x));
        hp[1] = f2bf(elu_f(acc[r].y + bv.y));
        hp[2] = f2bf(elu_f(acc[r].z + bv.z));
        hp[3] = f2bf(elu_f(acc[r].w + bv.w));
    }
    __syncthreads();

    const int wv   = t >> 6;
    const int lane = t & 63;
    const int lrow = lane & 15;
    const int lhi  = lane >> 4;

    for (int nt = wv * 2; nt < wv * 2 + 2; ++nt) {
        #pragma unroll
        for (int mt = 0; mt < 2; ++mt) {
            f32x4 acc2 = {0.f, 0.f, 0.f, 0.f};
            #pragma unroll
            for (int ks = 0; ks < 4; ++ks) {
                bf16x8 a = *reinterpret_cast<const bf16x8*>(
                    &h_s[(mt * 16 + lrow) * HPAD + ks * 32 + lhi * 8]);
                bf16x8 b = *reinterpret_cast<const bf16x8*>(
                    &w2t_s[(nt * 16 + lrow) * HPAD + ks * 32 + lhi * 8]);
                acc2 = __builtin_amdgcn_mfma_f32_16x16x32_bf16(a, b, acc2, 0, 0, 0);
            }
            int ncol = nt * 16 + lrow;
            float bias = b2[ncol];
            #pragma unroll
            for (int r = 0; r < 4; ++r) {
                int m = mt * 16 + lhi * 4 + r;
                out[(block_row0 + m) * HID + ncol] = elu_f(acc2[r] + bias);
            }
        }
    }
}

// ================= launch =================================================
extern "C" void kernel_launch(void* const* d_in, const int* in_sizes, int n_in,
                              void* d_out, int out_size, void* d_ws, size_t ws_size,
                              hipStream_t stream) {
    const int*   msg = (const int*)d_in[0];
    const float* W1  = (const float*)d_in[1];
    const float* b1  = (const float*)d_in[2];
    const float* W2  = (const float*)d_in[3];
    const float* b2  = (const float*)d_in[4];
    float* out = (float*)d_out;

    int Bn   = in_sizes[0] / NPOS;                   // 16384
    int grid = Bn / ROWS;                            // 1024

    // ws layout: [0..255] barrier counter (+pad), then w1b, then w2t
    const size_t w1b_elems = (size_t)NPOS * VOCABSZ * HID;          // 2,621,440
    const size_t need = 256 + (w1b_elems + (size_t)HID * HID) * 2;  // ~5.28 MB

    // Manual grid barrier requires all blocks co-resident:
    // 8 blocks/CU (launch_bounds 256,8; LDS 9.5KB) x 256 CU = 2048 capacity.
    if (ws_size >= need && grid <= 2048 && Bn % ROWS == 0) {
        unsigned int*   bar = (unsigned int*)d_ws;
        unsigned short* w1b = (unsigned short*)((char*)d_ws + 256);
        unsigned short* w2t = w1b + w1b_elems;
        hipMemsetAsync(d_ws, 0, 4, stream);          // zero barrier counter
        hipLaunchKernelGGL(topline_one, dim3(grid), dim3(NT), 0, stream,
                           msg, W1, b1, W2, b2, out, w1b, w2t, bar);
    } else {
        hipLaunchKernelGGL(topline_fused, dim3(Bn / FB_ROWS), dim3(FB_NT), 0, stream,
                           msg, W1, b1, W2, b2, out);
    }
}

// Round 6
// 46.195 us; speedup vs baseline: 2.9747x; 2.9747x over previous
//
#include <hip/hip_runtime.h>
#include <hip/hip_bf16.h>

#define NPOS 80
#define VOCABSZ 256
#define HID 128

typedef __attribute__((ext_vector_type(8))) short bf16x8;
typedef __attribute__((ext_vector_type(4))) float f32x4;
typedef __attribute__((ext_vector_type(4))) unsigned int u32x4;

__device__ __forceinline__ float elu_f(float x) {
    return x > 0.f ? x : expm1f(x);
}

__device__ __forceinline__ unsigned short f2bf(float x) {
    __hip_bfloat16 h = __float2bfloat16(x);  // RNE
    return *reinterpret_cast<unsigned short*>(&h);
}

// ================= prep: W1 fp32->bf16 table + W2 transpose->bf16 =========
#define PREP_W1_BLOCKS 2560   // 20480*128/4 float4 / 256 threads

__global__ __launch_bounds__(256)
void prep_tables(const float* __restrict__ W1, const float* __restrict__ W2,
                 unsigned short* __restrict__ w1b, unsigned short* __restrict__ w2t)
{
    const int b = blockIdx.x;
    const int t = threadIdx.x;
    if (b < PREP_W1_BLOCKS) {
        int idx = b * 256 + t;                       // float4 index
        float4 w = reinterpret_cast<const float4*>(W1)[idx];
        ushort4 o;
        o.x = f2bf(w.x); o.y = f2bf(w.y); o.z = f2bf(w.z); o.w = f2bf(w.w);
        reinterpret_cast<ushort4*>(w1b)[idx] = o;
    } else {
        int j = (b - PREP_W1_BLOCKS) * 256 + t;      // 0..4095
        #pragma unroll
        for (int q = 0; q < 4; ++q) {
            int e = j * 4 + q;                       // 0..16383 over W2 [k][n]
            int k = e >> 7, n = e & 127;
            w2t[n * HID + k] = f2bf(W2[e]);          // w2t[n][k]
        }
    }
}

// ================= main fused kernel (bf16 table path) ====================
// Proven r3 shape: 256 thr, 16 rows/block, 16 lanes x u32x4 per row,
// launch_bounds(256,8) -> 8 blocks/CU. Gather loads NON-TEMPORAL (L1 bypass
// experiment: probes whether the ~16 TB/s plateau is the per-CU L1 fill path).
#define ROWS 16
#define NT 256
#define MPAD 81      // msg row pitch (ints): conflict-free row reads
#define HPAD 136     // h row pitch (ushorts): 272B, 16B-aligned

__global__ __launch_bounds__(NT, 8)
void topline_bf16(const int* __restrict__ msg,
                  const unsigned short* __restrict__ w1b,
                  const float* __restrict__ b1,
                  const unsigned short* __restrict__ w2t,
                  const float* __restrict__ b2,
                  float* __restrict__ out)
{
    __shared__ int msg_s[ROWS * MPAD];               // 5184 B
    __shared__ unsigned short h_s[ROWS * HPAD];      // 4352 B

    const int t = threadIdx.x;
    const int block_row0 = blockIdx.x * ROWS;

    // ---- stage message rows ----
    const int* mrow = msg + block_row0 * NPOS;
    #pragma unroll
    for (int i = 0; i < 5; ++i) {
        int idx = t + i * NT;                        // < 1280
        int r = idx / NPOS;
        int c = idx - r * NPOS;
        msg_s[r * MPAD + c] = mrow[idx];
    }
    __syncthreads();

    // ---- gather: position-major sweep over bf16 table ----
    // thread (row = t>>4, lane16 = t&15) owns channels lane16*8..+7 of one row
    const int lane16 = t & 15;
    const int row    = t >> 4;
    const int mbase  = row * MPAD;
    const unsigned short* wb = w1b + lane16 * 8;     // channel offset folded in

    float acc[8];
    #pragma unroll
    for (int i = 0; i < 8; ++i) acc[i] = 0.f;

    #pragma unroll 4
    for (int p = 0; p < NPOS; ++p) {
        int c = msg_s[mbase + p];                    // broadcast across 16 lanes
        u32x4 v = __builtin_nontemporal_load(
            reinterpret_cast<const u32x4*>(wb + ((p * VOCABSZ + c) << 7)));
        // lo bf16: shift to hi half. hi bf16: add RAW (garbage low mantissa
        // bits perturb by <2^-8 relative; absmax-validated identical in r4/r5).
        acc[0] += __uint_as_float(v[0] << 16);
        acc[1] += __uint_as_float(v[0]);
        acc[2] += __uint_as_float(v[1] << 16);
        acc[3] += __uint_as_float(v[1]);
        acc[4] += __uint_as_float(v[2] << 16);
        acc[5] += __uint_as_float(v[2]);
        acc[6] += __uint_as_float(v[3] << 16);
        acc[7] += __uint_as_float(v[3]);
    }

    // ---- bias + elu + store h as bf16 ----
    {
        const float4 ba = reinterpret_cast<const float4*>(b1)[lane16 * 2];
        const float4 bb = reinterpret_cast<const float4*>(b1)[lane16 * 2 + 1];
        unsigned short* hp = &h_s[row * HPAD + lane16 * 8];
        hp[0] = f2bf(elu_f(acc[0] + ba.x));
        hp[1] = f2bf(elu_f(acc[1] + ba.y));
        hp[2] = f2bf(elu_f(acc[2] + ba.z));
        hp[3] = f2bf(elu_f(acc[3] + ba.w));
        hp[4] = f2bf(elu_f(acc[4] + bb.x));
        hp[5] = f2bf(elu_f(acc[5] + bb.y));
        hp[6] = f2bf(elu_f(acc[6] + bb.z));
        hp[7] = f2bf(elu_f(acc[7] + bb.w));
    }
    __syncthreads();

    // ---- MFMA: out[16,128] = elu(h @ W2 + b2); wave wv -> n-tiles 2wv,2wv+1 ----
    const int wv   = t >> 6;     // 0..3
    const int lane = t & 63;
    const int lrow = lane & 15;
    const int lhi  = lane >> 4;  // 0..3

    #pragma unroll
    for (int q = 0; q < 2; ++q) {
        int nt = wv * 2 + q;
        f32x4 c4 = {0.f, 0.f, 0.f, 0.f};
        #pragma unroll
        for (int ks = 0; ks < 4; ++ks) {
            bf16x8 a = *reinterpret_cast<const bf16x8*>(
                &h_s[lrow * HPAD + ks * 32 + lhi * 8]);
            bf16x8 bfr = *reinterpret_cast<const bf16x8*>(
                &w2t[(nt * 16 + lrow) * HID + ks * 32 + lhi * 8]);
            c4 = __builtin_amdgcn_mfma_f32_16x16x32_bf16(a, bfr, c4, 0, 0, 0);
        }
        int ncol = nt * 16 + lrow;
        float bias = b2[ncol];
        #pragma unroll
        for (int r = 0; r < 4; ++r)
            out[(block_row0 + lhi * 4 + r) * HID + ncol] = elu_f(c4[r] + bias);
    }
}

// ================= fallback (round-2 kernel, fp32 table, no ws) ===========
#define FB_ROWS 32
#define FB_NT 256

__global__ __launch_bounds__(FB_NT, 2)
void topline_fused(const int* __restrict__ msg,
                   const float* __restrict__ W1,
                   const float* __restrict__ b1,
                   const float* __restrict__ W2,
                   const float* __restrict__ b2,
                   float* __restrict__ out)
{
    __shared__ int msg_s[FB_ROWS * NPOS];
    __shared__ unsigned short h_s[FB_ROWS * HPAD];
    __shared__ unsigned short w2t_s[HID * HPAD];

    const int t = threadIdx.x;
    const int block_row0 = blockIdx.x * FB_ROWS;

    const int* mrow = msg + block_row0 * NPOS;
    #pragma unroll
    for (int i = 0; i < (FB_ROWS * NPOS) / FB_NT; ++i)
        msg_s[t + i * FB_NT] = mrow[t + i * FB_NT];

    const float4* W2v = reinterpret_cast<const float4*>(W2);
    #pragma unroll
    for (int i = 0; i < (HID * HID / 4) / FB_NT; ++i) {
        int i4 = t + i * FB_NT;
        int k  = i4 >> 5;
        int n0 = (i4 & 31) * 4;
        float4 w = W2v[i4];
        w2t_s[(n0 + 0) * HPAD + k] = f2bf(w.x);
        w2t_s[(n0 + 1) * HPAD + k] = f2bf(w.y);
        w2t_s[(n0 + 2) * HPAD + k] = f2bf(w.z);
        w2t_s[(n0 + 3) * HPAD + k] = f2bf(w.w);
    }
    __syncthreads();

    const int lane32 = t & 31;
    const int slot   = t >> 5;
    const int row0   = slot * 4;
    const float4* W1v = reinterpret_cast<const float4*>(W1);

    f32x4 acc[4];
    #pragma unroll
    for (int r = 0; r < 4; ++r) acc[r] = (f32x4){0.f, 0.f, 0.f, 0.f};

    #pragma unroll 2
    for (int p = 0; p < NPOS; ++p) {
        #pragma unroll
        for (int r = 0; r < 4; ++r) {
            int c = msg_s[(row0 + r) * NPOS + p];
            float4 w = W1v[(p * VOCABSZ + c) * (HID / 4) + lane32];
            acc[r].x += w.x; acc[r].y += w.y; acc[r].z += w.z; acc[r].w += w.w;
        }
    }

    const float4 bv = reinterpret_cast<const float4*>(b1)[lane32];
    #pragma unroll
    for (int r = 0; r < 4; ++r) {
        unsigned short* hp = &h_s[(row0 + r) * HPAD + lane32 * 4];
        hp[0] = f2bf(elu_f(acc[r].x + bv.x));
        hp[1] = f2bf(elu_f(acc[r].y + bv.y));
        hp[2] = f2bf(elu_f(acc[r].z + bv.z));
        hp[3] = f2bf(elu_f(acc[r].w + bv.w));
    }
    __syncthreads();

    const int wv   = t >> 6;
    const int lane = t & 63;
    const int lrow = lane & 15;
    const int lhi  = lane >> 4;

    for (int nt = wv * 2; nt < wv * 2 + 2; ++nt) {
        #pragma unroll
        for (int mt = 0; mt < 2; ++mt) {
            f32x4 acc2 = {0.f, 0.f, 0.f, 0.f};
            #pragma unroll
            for (int ks = 0; ks < 4; ++ks) {
                bf16x8 a = *reinterpret_cast<const bf16x8*>(
                    &h_s[(mt * 16 + lrow) * HPAD + ks * 32 + lhi * 8]);
                bf16x8 b = *reinterpret_cast<const bf16x8*>(
                    &w2t_s[(nt * 16 + lrow) * HPAD + ks * 32 + lhi * 8]);
                acc2 = __builtin_amdgcn_mfma_f32_16x16x32_bf16(a, b, acc2, 0, 0, 0);
            }
            int ncol = nt * 16 + lrow;
            float bias = b2[ncol];
            #pragma unroll
            for (int r = 0; r < 4; ++r) {
                int m = mt * 16 + lhi * 4 + r;
                out[(block_row0 + m) * HID + ncol] = elu_f(acc2[r] + bias);
            }
        }
    }
}

// ================= launch =================================================
extern "C" void kernel_launch(void* const* d_in, const int* in_sizes, int n_in,
                              void* d_out, int out_size, void* d_ws, size_t ws_size,
                              hipStream_t stream) {
    const int*   msg = (const int*)d_in[0];
    const float* W1  = (const float*)d_in[1];
    const float* b1  = (const float*)d_in[2];
    const float* W2  = (const float*)d_in[3];
    const float* b2  = (const float*)d_in[4];
    float* out = (float*)d_out;

    int Bn = in_sizes[0] / NPOS;                     // 16384

    const size_t w1b_elems = (size_t)NPOS * VOCABSZ * HID;      // 2,621,440
    const size_t need = (w1b_elems + (size_t)HID * HID) * 2;    // ~5.28 MB

    if (ws_size >= need && Bn % ROWS == 0) {
        unsigned short* w1b = (unsigned short*)d_ws;
        unsigned short* w2t = w1b + w1b_elems;
        hipLaunchKernelGGL(prep_tables, dim3(PREP_W1_BLOCKS + 16), dim3(256), 0, stream,
                           W1, W2, w1b, w2t);
        hipLaunchKernelGGL(topline_bf16, dim3(Bn / ROWS), dim3(NT), 0, stream,
                           msg, w1b, b1, w2t, b2, out);
    } else {
        hipLaunchKernelGGL(topline_fused, dim3(Bn / FB_ROWS), dim3(FB_NT), 0, stream,
                           msg, W1, b1, W2, b2, out);
    }
}

// Round 7
// 34.719 us; speedup vs baseline: 3.9580x; 1.3306x over previous
//
#include <hip/hip_runtime.h>
#include <hip/hip_bf16.h>

#define NPOS 80
#define VOCABSZ 256
#define HID 128

typedef __attribute__((ext_vector_type(8))) short bf16x8;
typedef __attribute__((ext_vector_type(4))) float f32x4;
typedef __attribute__((ext_vector_type(4))) unsigned int u32x4;

__device__ __forceinline__ float elu_f(float x) {
    return x > 0.f ? x : expm1f(x);
}

__device__ __forceinline__ unsigned short f2bf(float x) {
    __hip_bfloat16 h = __float2bfloat16(x);  // RNE
    return *reinterpret_cast<unsigned short*>(&h);
}

// ================= prep: W1 fp32->bf16 table + W2 transpose->bf16 =========
#define PREP_W1_BLOCKS 2560   // 20480*128/4 float4 / 256 threads

__global__ __launch_bounds__(256)
void prep_tables(const float* __restrict__ W1, const float* __restrict__ W2,
                 unsigned short* __restrict__ w1b, unsigned short* __restrict__ w2t)
{
    const int b = blockIdx.x;
    const int t = threadIdx.x;
    if (b < PREP_W1_BLOCKS) {
        int idx = b * 256 + t;                       // float4 index
        float4 w = reinterpret_cast<const float4*>(W1)[idx];
        ushort4 o;
        o.x = f2bf(w.x); o.y = f2bf(w.y); o.z = f2bf(w.z); o.w = f2bf(w.w);
        reinterpret_cast<ushort4*>(w1b)[idx] = o;
    } else {
        int j = (b - PREP_W1_BLOCKS) * 256 + t;      // 0..4095
        #pragma unroll
        for (int q = 0; q < 4; ++q) {
            int e = j * 4 + q;                       // 0..16383 over W2 [k][n]
            int k = e >> 7, n = e & 127;
            w2t[n * HID + k] = f2bf(W2[e]);          // w2t[n][k]
        }
    }
}

// ================= main fused kernel (bf16 table path) ====================
// r3 proven gather shape: 256 thr, 16 rows/block, 16 lanes x u32x4 per row.
// New: layer-2 operands (w2t frags, b1, b2) register-prefetched BEFORE the
// gather so their L2 latency hides under the 80-position sweep.
// launch_bounds(256,4): 4 blocks/CU (16 waves) -> 128-VGPR budget for the
// prefetch; gather plateau is occupancy-insensitive >=8 waves/CU (r2 vs r3).
#define ROWS 16
#define NT 256
#define MPAD 81      // msg row pitch (ints): conflict-free row reads
#define HPAD 136     // h row pitch (ushorts): 272B, 16B-aligned

__global__ __launch_bounds__(NT, 4)
void topline_bf16(const int* __restrict__ msg,
                  const unsigned short* __restrict__ w1b,
                  const float* __restrict__ b1,
                  const unsigned short* __restrict__ w2t,
                  const float* __restrict__ b2,
                  float* __restrict__ out)
{
    __shared__ int msg_s[ROWS * MPAD];               // 5184 B
    __shared__ unsigned short h_s[ROWS * HPAD];      // 4352 B

    const int t = threadIdx.x;
    const int block_row0 = blockIdx.x * ROWS;

    const int lane16 = t & 15;
    const int row    = t >> 4;
    const int wv     = t >> 6;     // wave 0..3
    const int lane   = t & 63;
    const int lrow   = lane & 15;
    const int lhi    = lane >> 4;  // 0..3

    // ---- stage message rows ----
    const int* mrow = msg + block_row0 * NPOS;
    #pragma unroll
    for (int i = 0; i < 5; ++i) {
        int idx = t + i * NT;                        // < 1280
        int r = idx / NPOS;
        int c = idx - r * NPOS;
        msg_s[r * MPAD + c] = mrow[idx];
    }

    // ---- prefetch layer-2 operands into registers (hide under gather) ----
    bf16x8 bfrag[2][4];
    float  bias2[2];
    #pragma unroll
    for (int q = 0; q < 2; ++q) {
        int nt_i = wv * 2 + q;
        #pragma unroll
        for (int ks = 0; ks < 4; ++ks)
            bfrag[q][ks] = *reinterpret_cast<const bf16x8*>(
                &w2t[(nt_i * 16 + lrow) * HID + ks * 32 + lhi * 8]);
        bias2[q] = b2[nt_i * 16 + lrow];
    }
    const float4 ba = reinterpret_cast<const float4*>(b1)[lane16 * 2];
    const float4 bb = reinterpret_cast<const float4*>(b1)[lane16 * 2 + 1];

    __syncthreads();

    // ---- gather: position-major sweep over bf16 table ----
    // thread (row, lane16) owns channels lane16*8..+7 of one row
    const int mbase  = row * MPAD;
    const unsigned short* wb = w1b + lane16 * 8;     // channel offset folded in

    float acc[8];
    #pragma unroll
    for (int i = 0; i < 8; ++i) acc[i] = 0.f;

    #pragma unroll 8
    for (int p = 0; p < NPOS; ++p) {
        int c = msg_s[mbase + p];                    // broadcast across 16 lanes
        u32x4 v = *reinterpret_cast<const u32x4*>(wb + ((p * VOCABSZ + c) << 7));
        // lo bf16: shift to hi half. hi bf16: add RAW (garbage low mantissa
        // bits perturb by <2^-8 relative; absmax-validated identical r3-r6).
        acc[0] += __uint_as_float(v[0] << 16);
        acc[1] += __uint_as_float(v[0]);
        acc[2] += __uint_as_float(v[1] << 16);
        acc[3] += __uint_as_float(v[1]);
        acc[4] += __uint_as_float(v[2] << 16);
        acc[5] += __uint_as_float(v[2]);
        acc[6] += __uint_as_float(v[3] << 16);
        acc[7] += __uint_as_float(v[3]);
    }

    // ---- bias + elu + store h as bf16 ----
    {
        unsigned short* hp = &h_s[row * HPAD + lane16 * 8];
        hp[0] = f2bf(elu_f(acc[0] + ba.x));
        hp[1] = f2bf(elu_f(acc[1] + ba.y));
        hp[2] = f2bf(elu_f(acc[2] + ba.z));
        hp[3] = f2bf(elu_f(acc[3] + ba.w));
        hp[4] = f2bf(elu_f(acc[4] + bb.x));
        hp[5] = f2bf(elu_f(acc[5] + bb.y));
        hp[6] = f2bf(elu_f(acc[6] + bb.z));
        hp[7] = f2bf(elu_f(acc[7] + bb.w));
    }
    __syncthreads();

    // ---- MFMA: out[16,128] = elu(h @ W2 + b2); wave wv -> n-tiles 2wv,2wv+1 ----
    #pragma unroll
    for (int q = 0; q < 2; ++q) {
        f32x4 c4 = {0.f, 0.f, 0.f, 0.f};
        #pragma unroll
        for (int ks = 0; ks < 4; ++ks) {
            bf16x8 a = *reinterpret_cast<const bf16x8*>(
                &h_s[lrow * HPAD + ks * 32 + lhi * 8]);
            c4 = __builtin_amdgcn_mfma_f32_16x16x32_bf16(a, bfrag[q][ks], c4, 0, 0, 0);
        }
        int ncol = (wv * 2 + q) * 16 + lrow;
        #pragma unroll
        for (int r = 0; r < 4; ++r)
            out[(block_row0 + lhi * 4 + r) * HID + ncol] = elu_f(c4[r] + bias2[q]);
    }
}

// ================= fallback (round-2 kernel, fp32 table, no ws) ===========
#define FB_ROWS 32
#define FB_NT 256

__global__ __launch_bounds__(FB_NT, 2)
void topline_fused(const int* __restrict__ msg,
                   const float* __restrict__ W1,
                   const float* __restrict__ b1,
                   const float* __restrict__ W2,
                   const float* __restrict__ b2,
                   float* __restrict__ out)
{
    __shared__ int msg_s[FB_ROWS * NPOS];
    __shared__ unsigned short h_s[FB_ROWS * HPAD];
    __shared__ unsigned short w2t_s[HID * HPAD];

    const int t = threadIdx.x;
    const int block_row0 = blockIdx.x * FB_ROWS;

    const int* mrow = msg + block_row0 * NPOS;
    #pragma unroll
    for (int i = 0; i < (FB_ROWS * NPOS) / FB_NT; ++i)
        msg_s[t + i * FB_NT] = mrow[t + i * FB_NT];

    const float4* W2v = reinterpret_cast<const float4*>(W2);
    #pragma unroll
    for (int i = 0; i < (HID * HID / 4) / FB_NT; ++i) {
        int i4 = t + i * FB_NT;
        int k  = i4 >> 5;
        int n0 = (i4 & 31) * 4;
        float4 w = W2v[i4];
        w2t_s[(n0 + 0) * HPAD + k] = f2bf(w.x);
        w2t_s[(n0 + 1) * HPAD + k] = f2bf(w.y);
        w2t_s[(n0 + 2) * HPAD + k] = f2bf(w.z);
        w2t_s[(n0 + 3) * HPAD + k] = f2bf(w.w);
    }
    __syncthreads();

    const int lane32 = t & 31;
    const int slot   = t >> 5;
    const int row0   = slot * 4;
    const float4* W1v = reinterpret_cast<const float4*>(W1);

    f32x4 acc[4];
    #pragma unroll
    for (int r = 0; r < 4; ++r) acc[r] = (f32x4){0.f, 0.f, 0.f, 0.f};

    #pragma unroll 2
    for (int p = 0; p < NPOS; ++p) {
        #pragma unroll
        for (int r = 0; r < 4; ++r) {
            int c = msg_s[(row0 + r) * NPOS + p];
            float4 w = W1v[(p * VOCABSZ + c) * (HID / 4) + lane32];
            acc[r].x += w.x; acc[r].y += w.y; acc[r].z += w.z; acc[r].w += w.w;
        }
    }

    const float4 bv = reinterpret_cast<const float4*>(b1)[lane32];
    #pragma unroll
    for (int r = 0; r < 4; ++r) {
        unsigned short* hp = &h_s[(row0 + r) * HPAD + lane32 * 4];
        hp[0] = f2bf(elu_f(acc[r].x + bv.x));
        hp[1] = f2bf(elu_f(acc[r].y + bv.y));
        hp[2] = f2bf(elu_f(acc[r].z + bv.z));
        hp[3] = f2bf(elu_f(acc[r].w + bv.w));
    }
    __syncthreads();

    const int wv   = t >> 6;
    const int lane = t & 63;
    const int lrow = lane & 15;
    const int lhi  = lane >> 4;

    for (int nt = wv * 2; nt < wv * 2 + 2; ++nt) {
        #pragma unroll
        for (int mt = 0; mt < 2; ++mt) {
            f32x4 acc2 = {0.f, 0.f, 0.f, 0.f};
            #pragma unroll
            for (int ks = 0; ks < 4; ++ks) {
                bf16x8 a = *reinterpret_cast<const bf16x8*>(
                    &h_s[(mt * 16 + lrow) * HPAD + ks * 32 + lhi * 8]);
                bf16x8 b = *reinterpret_cast<const bf16x8*>(
                    &w2t_s[(nt * 16 + lrow) * HPAD + ks * 32 + lhi * 8]);
                acc2 = __builtin_amdgcn_mfma_f32_16x16x32_bf16(a, b, acc2, 0, 0, 0);
            }
            int ncol = nt * 16 + lrow;
            float bias = b2[ncol];
            #pragma unroll
            for (int r = 0; r < 4; ++r) {
                int m = mt * 16 + lhi * 4 + r;
                out[(block_row0 + m) * HID + ncol] = elu_f(acc2[r] + bias);
            }
        }
    }
}

// ================= launch =================================================
extern "C" void kernel_launch(void* const* d_in, const int* in_sizes, int n_in,
                              void* d_out, int out_size, void* d_ws, size_t ws_size,
                              hipStream_t stream) {
    const int*   msg = (const int*)d_in[0];
    const float* W1  = (const float*)d_in[1];
    const float* b1  = (const float*)d_in[2];
    const float* W2  = (const float*)d_in[3];
    const float* b2  = (const float*)d_in[4];
    float* out = (float*)d_out;

    int Bn = in_sizes[0] / NPOS;                     // 16384

    const size_t w1b_elems = (size_t)NPOS * VOCABSZ * HID;      // 2,621,440
    const size_t need = (w1b_elems + (size_t)HID * HID) * 2;    // ~5.28 MB

    if (ws_size >= need && Bn % ROWS == 0) {
        unsigned short* w1b = (unsigned short*)d_ws;
        unsigned short* w2t = w1b + w1b_elems;
        hipLaunchKernelGGL(prep_tables, dim3(PREP_W1_BLOCKS + 16), dim3(256), 0, stream,
                           W1, W2, w1b, w2t);
        hipLaunchKernelGGL(topline_bf16, dim3(Bn / ROWS), dim3(NT), 0, stream,
                           msg, w1b, b1, w2t, b2, out);
    } else {
        hipLaunchKernelGGL(topline_fused, dim3(Bn / FB_ROWS), dim3(FB_NT), 0, stream,
                           msg, W1, b1, W2, b2, out);
    }
}